// Round 5
// baseline (605.693 us; speedup 1.0000x reference)
//
#include <hip/hip_runtime.h>
#include <cstddef>

constexpr int B = 2, H = 16, S = 2048, D = 128;
constexpr int BH = B * H;
constexpr int TWOD = 2 * D;          // 256
constexpr int QTILE = 64;            // q rows per block: 2 q-waves x 2 mtiles x 16
constexpr int BC = 32;               // keys per tile
constexpr int NKT = S / BC;          // 64
constexpr float SC2 = 0.08838834764831845f * 1.4426950408889634f; // (1/sqrt(128))*log2(e)
constexpr float LAM_INIT = 0.8f;
constexpr float GN_EPS = 1e-5f;

typedef __attribute__((ext_vector_type(8))) short short8;
typedef __attribute__((ext_vector_type(4))) float f32x4;

__device__ __forceinline__ unsigned short f2b(float f) {
  unsigned int u = __float_as_uint(f);
  u += 0x7fffu + ((u >> 16) & 1u);
  return (unsigned short)(u >> 16);
}

__device__ __forceinline__ void async_copy16(const void* g, void* l) {
  typedef __attribute__((address_space(1))) const void gvoid;
  typedef __attribute__((address_space(3))) void lvoid;
  __builtin_amdgcn_global_load_lds((gvoid*)g, (lvoid*)l, 16, 0, 0);
}

// ---------------- kernel 1: prep = K fp32->bf16 copy  +  V transpose  + lambda ----------------
// Merged convk (blocks 0..8191) and vt (blocks 8192..9215): one launch, overlapped BW.
__global__ void prep_kernel(const float* __restrict__ ksrc, unsigned short* __restrict__ kdst,
                            const float* __restrict__ v, unsigned short* __restrict__ vtg,
                            const float* __restrict__ lq1, const float* __restrict__ lq2,
                            const float* __restrict__ lk1, const float* __restrict__ lk2,
                            float* __restrict__ wsf) {
  __shared__ float tile[64][129];     // vt branch only; pitch 129: column reads <=2-way
  const int t = threadIdx.x;
  if (blockIdx.x < 8192) {
    if (blockIdx.x == 0 && t < 64) {
      float s1 = lq1[t] * lk1[t] + lq1[t + 64] * lk1[t + 64];
      float s2 = lq2[t] * lk2[t] + lq2[t + 64] * lk2[t + 64];
#pragma unroll
      for (int off = 32; off >= 1; off >>= 1) {
        s1 += __shfl_xor(s1, off, 64);
        s2 += __shfl_xor(s2, off, 64);
      }
      if (t == 0) wsf[0] = expf(s1) - expf(s2) + LAM_INIT;
    }
    size_t i = ((size_t)blockIdx.x * 256 + t) * 8;
    float4 a = *(const float4*)(ksrc + i);
    float4 b = *(const float4*)(ksrc + i + 4);
    unsigned short u[8];
    u[0] = f2b(a.x); u[1] = f2b(a.y); u[2] = f2b(a.z); u[3] = f2b(a.w);
    u[4] = f2b(b.x); u[5] = f2b(b.y); u[6] = f2b(b.z); u[7] = f2b(b.w);
    *(uint4*)(kdst + i) = *(uint4*)u;
  } else {
    const int bid = blockIdx.x - 8192;
    const int bh = bid >> 5, s0 = (bid & 31) * 64;
#pragma unroll
    for (int i = 0; i < 8; ++i) {
      int idx = t + i * 256;            // 2048 f4 chunks (64 s x 32 f4)
      int row = idx >> 5, c4 = idx & 31;
      float4 f = *(const float4*)(v + ((size_t)bh * S + s0 + row) * D + c4 * 4);
      tile[row][c4 * 4 + 0] = f.x; tile[row][c4 * 4 + 1] = f.y;
      tile[row][c4 * 4 + 2] = f.z; tile[row][c4 * 4 + 3] = f.w;
    }
    __syncthreads();
#pragma unroll
    for (int i = 0; i < 4; ++i) {
      int c = t + i * 256;              // 1024 chunks (128 d x 8 k-groups)
      int d = c >> 3, k8 = c & 7;
      unsigned short u[8];
#pragma unroll
      for (int j = 0; j < 8; ++j) u[j] = f2b(tile[k8 * 8 + j][d]);
      *(uint4*)(vtg + ((size_t)bh * D + d) * S + s0 + k8 * 8) = *(uint4*)u;
    }
  }
}

// ---------------- kernel 3: stream-split flash attention, counted-vmcnt schedule ----------------
// r3 dataflow (V LDS-staged, P in regs via shfl redistribution, waves=(stream,q-half))
// with the sync skeleton rebuilt per T3/T4/T5: ONE raw s_barrier per iter, counted
// s_waitcnt vmcnt(2) before it (K-DMA certified; V reg-loads stay in flight), vmcnt(0)
// only for the wave's own V regs after it. K(t+2) DMA issued after the barrier ->
// certified a full iteration later. No drain-to-0 of the DMA queue anywhere in the loop.
// setprio(1) wraps the qk+pv MFMA cluster.
// Hazards (re-derived): A(t+1) reads Vt written at I(t-1) [certified lgkmcnt(0)+G(t)];
// J(t) overwrites Ks read only before G(t); epilogue takes one extra lgkm+barrier
// before reading V(NKT-1).
__global__ __launch_bounds__(256, 3)
void attn_kernel(const float* __restrict__ q, const unsigned short* __restrict__ kbf,
                 const unsigned short* __restrict__ vtg,
                 float* __restrict__ wsf, float* __restrict__ out) {
  __shared__ __attribute__((aligned(16))) unsigned char smem_raw[53248];
  __shared__ float sred[2][2];
  unsigned short (*Ks)[32][256] = (unsigned short (*)[32][256])smem_raw;          // [2][32][256]
  unsigned short (*Vt)[128][40] = (unsigned short (*)[128][40])(smem_raw + 32768);// [2][128][40]
  float (*Ob)[132] = (float (*)[132])smem_raw;                                    // [64][132] epilogue overlay

  const int bh = blockIdx.x, qb = blockIdx.y;
  const int q0 = qb * QTILE;
  const int tid = threadIdx.x;
  const int wave = tid >> 6, lane = tid & 63;
  const int st = wave & 1, wq = wave >> 1;
  const int quad = lane >> 4, l16 = lane & 15;
  const float lam = wsf[0];

  // ---- register-resident bf16 Q fragments (A-layout), pre-scaled by SC2 ----
  short8 qf[2][4];                    // [mtile][kstep], stream st only
#pragma unroll
  for (int mt = 0; mt < 2; ++mt) {
    int qrow = q0 + wq * 32 + mt * 16 + l16;
    const float* qr = q + ((size_t)bh * S + qrow) * TWOD + st * D;
#pragma unroll
    for (int ks = 0; ks < 4; ++ks) {
      const float* p = qr + ks * 32 + quad * 8;
      float4 f0 = *(const float4*)p;
      float4 f1 = *(const float4*)(p + 4);
      short8 v8;
      v8[0] = (short)f2b(f0.x * SC2); v8[1] = (short)f2b(f0.y * SC2);
      v8[2] = (short)f2b(f0.z * SC2); v8[3] = (short)f2b(f0.w * SC2);
      v8[4] = (short)f2b(f1.x * SC2); v8[5] = (short)f2b(f1.y * SC2);
      v8[6] = (short)f2b(f1.z * SC2); v8[7] = (short)f2b(f1.w * SC2);
      qf[mt][ks] = v8;
    }
  }

  // ---- staging addresses ----
  const unsigned short* kbase = kbf + (size_t)bh * S * (size_t)TWOD;
  int goff[4];
#pragma unroll
  for (int i = 0; i < 4; ++i) {
    int L = i * 256 + tid;
    int row = L >> 5, cp = L & 31;
    int g = cp ^ (row & 7);
    goff[i] = row * 256 + g * 8;
  }
  const unsigned short* vbase = vtg + (size_t)bh * D * (size_t)S;
  const int vd0 = tid >> 2, vcp = tid & 3;

  f32x4 acc[2][8];                    // [mtile][d-tile] for this wave's stream
#pragma unroll
  for (int mt = 0; mt < 2; ++mt)
#pragma unroll
    for (int n = 0; n < 8; ++n) acc[mt][n] = (f32x4){0.f, 0.f, 0.f, 0.f};
  float lacc[2] = {0.f, 0.f};

  short8 pa[2];                       // P(t-1) A-frags, carried in registers
  {
    uint4 z4 = {0u, 0u, 0u, 0u};
    pa[0] = *(short8*)&z4; pa[1] = *(short8*)&z4;
  }
  const int stq = st * 16;            // K column group for this stream
  const int srcA = ((quad * 2) & 3) * 16 + l16;      // shfl sources for P redistribution
  const int srcB = ((quad * 2 + 1) & 3) * 16 + l16;
  const bool hi = quad >= 2;

  auto qk = [&](int kb, f32x4 (&sa)[2][2]) {
#pragma unroll
    for (int nt = 0; nt < 2; ++nt) {
      const int row = nt * 16 + l16;
      const int rx = row & 7;
#pragma unroll
      for (int ks = 0; ks < 4; ++ks) {
        const int pos = (stq + ks * 4 + quad) ^ rx;
        const short8 kf = *(const short8*)&Ks[kb][row][pos * 8];
        // swapped operands: D[m=key][n=q] -> lane holds 4 consecutive keys
        sa[0][nt] = __builtin_amdgcn_mfma_f32_16x16x32_bf16(kf, qf[0][ks], sa[0][nt], 0, 0, 0);
        sa[1][nt] = __builtin_amdgcn_mfma_f32_16x16x32_bf16(kf, qf[1][ks], sa[1][nt], 0, 0, 0);
      }
    }
  };
  // exp + pack + in-register redistribution to PV A-frag layout (writes pa[])
  auto pexp_redist = [&](f32x4 (&sa)[2][2]) {
#pragma unroll
    for (int mt = 0; mt < 2; ++mt) {
      unsigned int w[2][2];
#pragma unroll
      for (int nt = 0; nt < 2; ++nt) {
        float p0 = __builtin_amdgcn_exp2f(sa[mt][nt][0]);
        float p1 = __builtin_amdgcn_exp2f(sa[mt][nt][1]);
        float p2 = __builtin_amdgcn_exp2f(sa[mt][nt][2]);
        float p3 = __builtin_amdgcn_exp2f(sa[mt][nt][3]);
        lacc[mt] += (p0 + p1) + (p2 + p3);
        w[nt][0] = (unsigned int)f2b(p0) | ((unsigned int)f2b(p1) << 16);
        w[nt][1] = (unsigned int)f2b(p2) | ((unsigned int)f2b(p3) << 16);
      }
      unsigned int a0 = (unsigned int)__shfl((int)w[0][0], srcA, 64);
      unsigned int a1 = (unsigned int)__shfl((int)w[0][1], srcA, 64);
      unsigned int a2 = (unsigned int)__shfl((int)w[0][0], srcB, 64);
      unsigned int a3 = (unsigned int)__shfl((int)w[0][1], srcB, 64);
      unsigned int b0 = (unsigned int)__shfl((int)w[1][0], srcA, 64);
      unsigned int b1 = (unsigned int)__shfl((int)w[1][1], srcA, 64);
      unsigned int b2 = (unsigned int)__shfl((int)w[1][0], srcB, 64);
      unsigned int b3 = (unsigned int)__shfl((int)w[1][1], srcB, 64);
      uint4 pu;
      pu.x = hi ? b0 : a0;
      pu.y = hi ? b1 : a1;
      pu.z = hi ? b2 : a2;
      pu.w = hi ? b3 : a3;
      pa[mt] = *(short8*)&pu;
    }
  };
  auto pv = [&](const short8 (&vf)[8]) {
#pragma unroll
    for (int nt8 = 0; nt8 < 8; ++nt8)
#pragma unroll
      for (int mt = 0; mt < 2; ++mt)
        acc[mt][nt8] = __builtin_amdgcn_mfma_f32_16x16x32_bf16(pa[mt], vf[nt8], acc[mt][nt8], 0, 0, 0);
  };

  // ---- prologue ----
  {
    const uint4 z = {0u, 0u, 0u, 0u};
    unsigned short* vz = &Vt[1][0][0];
    for (int i = tid; i < 640; i += 256) *(uint4*)(vz + i * 8) = z;   // Vt[1]=0 (iter0 reads it, pa=0)
#pragma unroll
    for (int i = 0; i < 4; ++i)                                       // DMA K(0) -> Ks[0]
      async_copy16(kbase + goff[i], &Ks[0][0][0] + (i * 256 + tid) * 8);
    uint4 v0 = *(const uint4*)(vbase + (size_t)vd0 * S + vcp * 8);    // V(0) -> regs
    uint4 v1 = *(const uint4*)(vbase + (size_t)(vd0 + 64) * S + vcp * 8);
    asm volatile("s_waitcnt vmcnt(0)\n\ts_waitcnt lgkmcnt(0)" ::: "memory");
    __builtin_amdgcn_s_barrier();
    *(uint4*)&Vt[0][vd0][vcp * 8] = v0;                               // Vt[0] = V(0)
    *(uint4*)&Vt[0][vd0 + 64][vcp * 8] = v1;
    const unsigned short* kp = kbase + (size_t)BC * TWOD;             // DMA K(1) -> Ks[1]
#pragma unroll
    for (int i = 0; i < 4; ++i)
      async_copy16(kp + goff[i], &Ks[1][0][0] + (i * 256 + tid) * 8);
  }

  // ---- main loop t = 0..NKT-2; entering: Ks[t&1]=K(t) certified, Vt[(t&1)^1]=V(t-1),
  //      outstanding: 4 DMA K(t+1) ----
  for (int t = 0; t < NKT - 1; ++t) {
    const int kb = t & 1;
    const int pvb = kb ^ 1;

    // A: V(t-1) B-frags from LDS
    short8 vf[8];
#pragma unroll
    for (int nt8 = 0; nt8 < 8; ++nt8)
      vf[nt8] = *(const short8*)&Vt[pvb][nt8 * 16 + l16][quad * 8];

    // B: V(t+1) -> regs (stays in flight past the barrier)
    const unsigned short* vp = vbase + (t + 1) * BC + vcp * 8;
    uint4 vr0 = *(const uint4*)(vp + (size_t)vd0 * S);
    uint4 vr1 = *(const uint4*)(vp + (size_t)(vd0 + 64) * S);

    // C+D: MFMA cluster at raised priority
    f32x4 sa[2][2];
#pragma unroll
    for (int mt = 0; mt < 2; ++mt)
#pragma unroll
      for (int nt = 0; nt < 2; ++nt) sa[mt][nt] = (f32x4){0.f, 0.f, 0.f, 0.f};
    __builtin_amdgcn_s_setprio(1);
    qk(kb, sa);
    pv(vf);                          // uses pa = P(t-1)
    __builtin_amdgcn_s_setprio(0);
    // E:
    pexp_redist(sa);                 // pa = P(t)

    // F: own ds ops drained (write-visibility for G); K(t+1) DMA done; V loads may fly
    asm volatile("s_waitcnt lgkmcnt(0)\n\ts_waitcnt vmcnt(2)" ::: "memory");
    // G: the only barrier
    __builtin_amdgcn_s_barrier();
    // H: own V(t+1) regs ready
    asm volatile("s_waitcnt vmcnt(0)" ::: "memory");
    // I: Vt[pvb] <- V(t+1) (all readers of V(t-1) passed G)
    *(uint4*)&Vt[pvb][vd0][vcp * 8] = vr0;
    *(uint4*)&Vt[pvb][vd0 + 64][vcp * 8] = vr1;
    // J: DMA K(t+2) -> Ks[kb] (K(t) readers passed G)
    if (t < NKT - 2) {
      const unsigned short* kp = kbase + (size_t)(t + 2) * BC * TWOD;
      unsigned short* ldsb = &Ks[kb][0][0];
#pragma unroll
      for (int i = 0; i < 4; ++i)
        async_copy16(kp + goff[i], ldsb + (i * 256 + tid) * 8);
    }
  }

  // ---- epilogue iter t = NKT-1 (odd): qk + pv(P(NKT-2)) + final pv(P(NKT-1)) ----
  {
    const int kb = (NKT - 1) & 1, pvb = kb ^ 1;
    short8 vf[8];
#pragma unroll
    for (int nt8 = 0; nt8 < 8; ++nt8)
      vf[nt8] = *(const short8*)&Vt[pvb][nt8 * 16 + l16][quad * 8];   // V(NKT-2)
    f32x4 sa[2][2];
#pragma unroll
    for (int mt = 0; mt < 2; ++mt)
#pragma unroll
      for (int nt = 0; nt < 2; ++nt) sa[mt][nt] = (f32x4){0.f, 0.f, 0.f, 0.f};
    qk(kb, sa);
    pv(vf);                          // P(NKT-2) x V(NKT-2)
    pexp_redist(sa);                 // pa = P(NKT-1)
    asm volatile("s_waitcnt lgkmcnt(0)" ::: "memory");
    __builtin_amdgcn_s_barrier();    // all I(NKT-2) writes of V(NKT-1) visible
    short8 vf2[8];
#pragma unroll
    for (int nt8 = 0; nt8 < 8; ++nt8)
      vf2[nt8] = *(const short8*)&Vt[kb][nt8 * 16 + l16][quad * 8];   // V(NKT-1)
    pv(vf2);                         // P(NKT-1) x V(NKT-1)
  }

  // ---- softmax denominators: per-lane partial covers quad's keys; reduce across quads ----
#pragma unroll
  for (int mt = 0; mt < 2; ++mt) {
    float v = lacc[mt];
    v += __shfl_xor(v, 16, 64);
    v += __shfl_xor(v, 32, 64);
    lacc[mt] = v;                    // denom for q-row = mt*16 + l16 (all lanes)
  }

  // ---- combine streams: st=1 writes lam-scaled contribution to LDS overlay ----
  const int obase = wq * 32;
  __syncthreads();                   // Ks fully dead (epilogue reads done block-wide)
  if (st == 1) {
#pragma unroll
    for (int mt = 0; mt < 2; ++mt) {
      float i2[4];
#pragma unroll
      for (int r = 0; r < 4; ++r) i2[r] = lam / __shfl(lacc[mt], quad * 4 + r, 64);
#pragma unroll
      for (int nt8 = 0; nt8 < 8; ++nt8)
#pragma unroll
        for (int r = 0; r < 4; ++r)
          Ob[obase + mt * 16 + quad * 4 + r][nt8 * 16 + l16] = acc[mt][nt8][r] * i2[r];
    }
  }
  __syncthreads();
  if (st == 0) {
    float sum = 0.f, ssq = 0.f;
#pragma unroll
    for (int mt = 0; mt < 2; ++mt) {
      float i1[4];
#pragma unroll
      for (int r = 0; r < 4; ++r) i1[r] = 1.f / __shfl(lacc[mt], quad * 4 + r, 64);
#pragma unroll
      for (int nt8 = 0; nt8 < 8; ++nt8)
#pragma unroll
        for (int r = 0; r < 4; ++r) {
          float o = acc[mt][nt8][r] * i1[r]
                  - Ob[obase + mt * 16 + quad * 4 + r][nt8 * 16 + l16];
          int row = q0 + obase + mt * 16 + quad * 4 + r;
          out[((size_t)bh * S + row) * D + nt8 * 16 + l16] = o;
          sum += o; ssq += o * o;
        }
    }
#pragma unroll
    for (int off = 32; off >= 1; off >>= 1) {
      sum += __shfl_xor(sum, off, 64);
      ssq += __shfl_xor(ssq, off, 64);
    }
    if (lane == 0) { sred[wq][0] = sum; sred[wq][1] = ssq; }
  }
  __syncthreads();
  if (tid == 0) {
    float s0 = sred[0][0] + sred[1][0];
    float s1 = sred[0][1] + sred[1][1];
    int idx = bh * 32 + qb;
    wsf[64 + idx * 2] = s0;
    wsf[64 + idx * 2 + 1] = s1;
  }
}

// ---------------- kernel 4: group norm (in-place on out) ----------------
__global__ void gn_kernel(float* __restrict__ out, const float* __restrict__ gw,
                          const float* __restrict__ gb, const float* __restrict__ wsf) {
  const int bh = blockIdx.x, part = blockIdx.y;
  const int h = bh & (H - 1);
  float sum = 0.f, ssq = 0.f;
  for (int j = 0; j < 32; ++j) {
    sum += wsf[64 + (bh * 32 + j) * 2];
    ssq += wsf[64 + (bh * 32 + j) * 2 + 1];
  }
  const float invn = 1.f / (float)(S * D);
  const float mean = sum * invn;
  const float var = ssq * invn - mean * mean;
  const float rstd = rsqrtf(var + GN_EPS);
  const float outscale = 1.f - LAM_INIT;
  const float4* g4 = (const float4*)(gw + h * D);
  const float4* b4 = (const float4*)(gb + h * D);
  float4* o4 = (float4*)(out + (size_t)bh * S * D);
  const int chunks_per = (S * D / 4) / 8;
  const int c0 = part * chunks_per;
  for (int c = c0 + threadIdx.x; c < c0 + chunks_per; c += 256) {
    float4 vv = o4[c];
    int d4 = c & 31;
    float4 g = g4[d4], bb = b4[d4];
    vv.x = ((vv.x - mean) * rstd * g.x + bb.x) * outscale;
    vv.y = ((vv.y - mean) * rstd * g.y + bb.y) * outscale;
    vv.z = ((vv.z - mean) * rstd * g.z + bb.z) * outscale;
    vv.w = ((vv.w - mean) * rstd * g.w + bb.w) * outscale;
    o4[c] = vv;
  }
}

extern "C" void kernel_launch(void* const* d_in, const int* in_sizes, int n_in,
                              void* d_out, int out_size, void* d_ws, size_t ws_size,
                              hipStream_t stream) {
  (void)in_sizes; (void)n_in; (void)out_size; (void)ws_size;
  const float* q   = (const float*)d_in[0];
  const float* k   = (const float*)d_in[1];
  const float* v   = (const float*)d_in[2];
  const float* lq1 = (const float*)d_in[3];
  const float* lq2 = (const float*)d_in[4];
  const float* lk1 = (const float*)d_in[5];
  const float* lk2 = (const float*)d_in[6];
  const float* gw  = (const float*)d_in[7];
  const float* gb  = (const float*)d_in[8];
  float* out = (float*)d_out;
  float* wsf = (float*)d_ws;
  unsigned short* vtg = (unsigned short*)((char*)d_ws + 16384);
  unsigned short* kbf = (unsigned short*)((char*)d_ws + 16384 + (size_t)BH * D * S * 2);

  prep_kernel<<<dim3(8192 + BH * 32), dim3(256), 0, stream>>>(k, kbf, v, vtg, lq1, lq2, lk1, lk2, wsf);
  attn_kernel<<<dim3(BH, S / QTILE), dim3(256), 0, stream>>>(q, kbf, vtg, wsf, out);
  gn_kernel<<<dim3(BH, 8), dim3(256), 0, stream>>>(out, gw, gb, wsf);
}

// Round 6
// 384.296 us; speedup vs baseline: 1.5761x; 1.5761x over previous
//
#include <hip/hip_runtime.h>
#include <cstddef>

constexpr int B = 2, H = 16, S = 2048, D = 128;
constexpr int BH = B * H;
constexpr int TWOD = 2 * D;          // 256
constexpr int QTILE = 128;           // q rows per block: 4 waves x 2 mtiles x 16
constexpr int BC = 32;               // keys per tile
constexpr int NKT = S / BC;          // 64
constexpr float SC2 = 0.08838834764831845f * 1.4426950408889634f; // (1/sqrt(128))*log2(e)
constexpr float LAM_INIT = 0.8f;
constexpr float GN_EPS = 1e-5f;

typedef __attribute__((ext_vector_type(8))) short short8;
typedef __attribute__((ext_vector_type(4))) float f32x4;

__device__ __forceinline__ unsigned short f2b(float f) {
  unsigned int u = __float_as_uint(f);
  u += 0x7fffu + ((u >> 16) & 1u);
  return (unsigned short)(u >> 16);
}

__device__ __forceinline__ void async_copy16(const void* g, void* l) {
  typedef __attribute__((address_space(1))) const void gvoid;
  typedef __attribute__((address_space(3))) void lvoid;
  __builtin_amdgcn_global_load_lds((gvoid*)g, (lvoid*)l, 16, 0, 0);
}

// ---------------- kernel 1: prep = K fp32->bf16 copy + V transpose + lambda ----------------
// Merged convk (blocks 0..8191) and vt (blocks 8192..9215): one launch, overlapped BW.
// (Correctness-proven in round 5; saves one ~30us launch slot vs separate kernels.)
__global__ void prep_kernel(const float* __restrict__ ksrc, unsigned short* __restrict__ kdst,
                            const float* __restrict__ v, unsigned short* __restrict__ vtg,
                            const float* __restrict__ lq1, const float* __restrict__ lq2,
                            const float* __restrict__ lk1, const float* __restrict__ lk2,
                            float* __restrict__ wsf) {
  __shared__ float tile[64][129];     // vt branch only; pitch 129: column reads <=2-way
  const int t = threadIdx.x;
  if (blockIdx.x < 8192) {
    if (blockIdx.x == 0 && t < 64) {
      float s1 = lq1[t] * lk1[t] + lq1[t + 64] * lk1[t + 64];
      float s2 = lq2[t] * lk2[t] + lq2[t + 64] * lk2[t + 64];
#pragma unroll
      for (int off = 32; off >= 1; off >>= 1) {
        s1 += __shfl_xor(s1, off, 64);
        s2 += __shfl_xor(s2, off, 64);
      }
      if (t == 0) wsf[0] = expf(s1) - expf(s2) + LAM_INIT;
    }
    size_t i = ((size_t)blockIdx.x * 256 + t) * 8;
    float4 a = *(const float4*)(ksrc + i);
    float4 b = *(const float4*)(ksrc + i + 4);
    unsigned short u[8];
    u[0] = f2b(a.x); u[1] = f2b(a.y); u[2] = f2b(a.z); u[3] = f2b(a.w);
    u[4] = f2b(b.x); u[5] = f2b(b.y); u[6] = f2b(b.z); u[7] = f2b(b.w);
    *(uint4*)(kdst + i) = *(uint4*)u;
  } else {
    const int bid = blockIdx.x - 8192;
    const int bh = bid >> 5, s0 = (bid & 31) * 64;
#pragma unroll
    for (int i = 0; i < 8; ++i) {
      int idx = t + i * 256;            // 2048 f4 chunks (64 s x 32 f4)
      int row = idx >> 5, c4 = idx & 31;
      float4 f = *(const float4*)(v + ((size_t)bh * S + s0 + row) * D + c4 * 4);
      tile[row][c4 * 4 + 0] = f.x; tile[row][c4 * 4 + 1] = f.y;
      tile[row][c4 * 4 + 2] = f.z; tile[row][c4 * 4 + 3] = f.w;
    }
    __syncthreads();
#pragma unroll
    for (int i = 0; i < 4; ++i) {
      int c = t + i * 256;              // 1024 chunks (128 d x 8 k-groups)
      int d = c >> 3, k8 = c & 7;
      unsigned short u[8];
#pragma unroll
      for (int j = 0; j < 8; ++j) u[j] = f2b(tile[k8 * 8 + j][d]);
      *(uint4*)(vtg + ((size_t)bh * D + d) * S + s0 + k8 * 8) = *(uint4*)u;
    }
  }
}

// ---------------- kernel 3: dual-stream flash attention (r2 verbatim, best: 230us) ----------------
// Swapped QK^T (mfma(kf,qf)): lane holds P for fixed q-row (l16) at 4
// consecutive keys (quad*4+r) -> packed uint2 P-writes (8x ds_write_b64/iter),
// scalar lacc, denominator redistribution via shfl. Softmax scale folded into
// Q->bf16 conversion. PV(t-1) overlaps QK(t); 1 barrier/iter.
// NOTE (r5 lesson): do NOT graft asm waitcnt/barriers into this loop --
// it fragments regalloc and spills (+160MB scratch traffic, 2x slower).
__global__ __launch_bounds__(256, 2)
void attn_kernel(const float* __restrict__ q, const unsigned short* __restrict__ kbf,
                 const unsigned short* __restrict__ vtg,
                 float* __restrict__ wsf, float* __restrict__ out) {
  __shared__ __attribute__((aligned(16))) unsigned short Ks[2][32][256];  // async dest, chunk-swizzled
  __shared__ __attribute__((aligned(16))) unsigned short Vt[2][128][40];  // pitch 40
  __shared__ __attribute__((aligned(16))) unsigned short Pa[4][2][32][40];// wave-private [q][k], pitch 40
  __shared__ float sred[4][2];

  const int bh = blockIdx.x, qb = blockIdx.y;
  const int q0 = qb * QTILE;
  const int tid = threadIdx.x;
  const int wave = tid >> 6, lane = tid & 63;
  const int quad = lane >> 4, l16 = lane & 15;
  const float lam = wsf[0];

  // ---- register-resident bf16 Q fragments (A-layout), pre-scaled by SC2 ----
  short8 qf[2][2][4];                 // [mtile][stream][kstep]
#pragma unroll
  for (int mt = 0; mt < 2; ++mt) {
    int qrow = q0 + wave * 32 + mt * 16 + l16;
    const float* qr = q + ((size_t)bh * S + qrow) * TWOD;
#pragma unroll
    for (int st = 0; st < 2; ++st)
#pragma unroll
      for (int ks = 0; ks < 4; ++ks) {
        const float* p = qr + st * D + ks * 32 + quad * 8;
        float4 f0 = *(const float4*)p;
        float4 f1 = *(const float4*)(p + 4);
        short8 v8;
        v8[0] = (short)f2b(f0.x * SC2); v8[1] = (short)f2b(f0.y * SC2);
        v8[2] = (short)f2b(f0.z * SC2); v8[3] = (short)f2b(f0.w * SC2);
        v8[4] = (short)f2b(f1.x * SC2); v8[5] = (short)f2b(f1.y * SC2);
        v8[6] = (short)f2b(f1.z * SC2); v8[7] = (short)f2b(f1.w * SC2);
        qf[mt][st][ks] = v8;
      }
  }

  // ---- staging addresses ----
  const unsigned short* kbase = kbf + (size_t)bh * S * (size_t)TWOD;
  int goff[4];
#pragma unroll
  for (int i = 0; i < 4; ++i) {
    int L = i * 256 + tid;
    int row = L >> 5, cp = L & 31;
    int g = cp ^ (row & 7);
    goff[i] = row * 256 + g * 8;
  }
  const unsigned short* vbase = vtg + (size_t)bh * D * (size_t)S;
  const int vd0 = tid >> 2, vcp = tid & 3;

  f32x4 acc[2][2][8];
#pragma unroll
  for (int mt = 0; mt < 2; ++mt)
#pragma unroll
    for (int st = 0; st < 2; ++st)
#pragma unroll
      for (int n = 0; n < 8; ++n) acc[mt][st][n] = (f32x4){0.f, 0.f, 0.f, 0.f};
  float lacc[2][2];
#pragma unroll
  for (int mt = 0; mt < 2; ++mt)
#pragma unroll
    for (int st = 0; st < 2; ++st) lacc[mt][st] = 0.f;

  // ---- QK / exp+Pwrite / PV as lambdas ----
  auto qk = [&](int st, int kb, f32x4 (&sa)[2][2]) {
#pragma unroll
    for (int nt = 0; nt < 2; ++nt) {
      const int row = nt * 16 + l16;
      const int rx = row & 7;
#pragma unroll
      for (int ks = 0; ks < 4; ++ks) {
        const int pos = (st * 16 + ks * 4 + quad) ^ rx;
        const short8 kf = *(const short8*)&Ks[kb][row][pos * 8];
        // swapped operands: D[m=key][n=q] -> lane holds 4 consecutive keys
        sa[0][nt] = __builtin_amdgcn_mfma_f32_16x16x32_bf16(kf, qf[0][st][ks], sa[0][nt], 0, 0, 0);
        sa[1][nt] = __builtin_amdgcn_mfma_f32_16x16x32_bf16(kf, qf[1][st][ks], sa[1][nt], 0, 0, 0);
      }
    }
  };
  auto pexp = [&](int st, f32x4 (&sa)[2][2]) {
#pragma unroll
    for (int mt = 0; mt < 2; ++mt)
#pragma unroll
      for (int nt = 0; nt < 2; ++nt) {
        float p0 = __builtin_amdgcn_exp2f(sa[mt][nt][0]);
        float p1 = __builtin_amdgcn_exp2f(sa[mt][nt][1]);
        float p2 = __builtin_amdgcn_exp2f(sa[mt][nt][2]);
        float p3 = __builtin_amdgcn_exp2f(sa[mt][nt][3]);
        lacc[mt][st] += (p0 + p1) + (p2 + p3);
        uint2 w;
        w.x = (unsigned int)f2b(p0) | ((unsigned int)f2b(p1) << 16);
        w.y = (unsigned int)f2b(p2) | ((unsigned int)f2b(p3) << 16);
        *(uint2*)&Pa[wave][st][mt * 16 + l16][nt * 16 + quad * 4] = w;
      }
  };
  auto pv = [&](int st, const short8 (&paf)[2], const short8 (&vf)[8]) {
#pragma unroll
    for (int nt8 = 0; nt8 < 8; ++nt8)
#pragma unroll
      for (int mt = 0; mt < 2; ++mt)
        acc[mt][st][nt8] = __builtin_amdgcn_mfma_f32_16x16x32_bf16(paf[mt], vf[nt8], acc[mt][st][nt8], 0, 0, 0);
  };

  // ---- prologue: zero Pa + Vt[1] (so PV(-1) adds exact zeros), stage tile 0 ----
  {
    const uint4 z = {0u, 0u, 0u, 0u};
    unsigned short* pz = &Pa[0][0][0][0];
    for (int i = tid; i < 1280; i += 256) *(uint4*)(pz + i * 8) = z;  // 20480 B
    unsigned short* vz = &Vt[1][0][0];
    for (int i = tid; i < 640; i += 256) *(uint4*)(vz + i * 8) = z;   // 10240 B
#pragma unroll
    for (int i = 0; i < 4; ++i)
      async_copy16(kbase + goff[i], &Ks[0][0][0] + (i * 256 + tid) * 8);
    uint4 v0 = *(const uint4*)(vbase + (size_t)vd0 * S + vcp * 8);
    uint4 v1 = *(const uint4*)(vbase + (size_t)(vd0 + 64) * S + vcp * 8);
    *(uint4*)&Vt[0][vd0][vcp * 8] = v0;
    *(uint4*)&Vt[0][vd0 + 64][vcp * 8] = v1;
  }
  __syncthreads();

  for (int t = 0; t < NKT; ++t) {
    const int kbuf = t & 1;
    const int pvbuf = kbuf ^ 1;      // holds V(t-1); also target for K(t+1)/V(t+1)

    // ---- top-of-iter LDS reads: P(t-1) A-frags + V(t-1) B-frags ----
    short8 paf[2][2], vf[8];
#pragma unroll
    for (int st = 0; st < 2; ++st)
#pragma unroll
      for (int mt = 0; mt < 2; ++mt)
        paf[st][mt] = *(const short8*)&Pa[wave][st][mt * 16 + l16][quad * 8];
#pragma unroll
    for (int nt8 = 0; nt8 < 8; ++nt8)
      vf[nt8] = *(const short8*)&Vt[pvbuf][nt8 * 16 + l16][quad * 8];

    // ---- prefetch tile t+1 ----
    const bool pre = (t + 1 < NKT);
    uint4 vr0, vr1;
    if (pre) {
      const unsigned short* vp = vbase + (t + 1) * BC + vcp * 8;
      vr0 = *(const uint4*)(vp + (size_t)vd0 * S);
      vr1 = *(const uint4*)(vp + (size_t)(vd0 + 64) * S);
      const unsigned short* kp = kbase + (size_t)(t + 1) * BC * TWOD;
      unsigned short* ldsb = &Ks[pvbuf][0][0];
#pragma unroll
      for (int i = 0; i < 4; ++i)
        async_copy16(kp + goff[i], ldsb + (i * 256 + tid) * 8);
    }

    // ---- pipelined compute: QK(t) interleaved with PV(t-1) ----
    f32x4 sa0[2][2], sa1[2][2];
#pragma unroll
    for (int mt = 0; mt < 2; ++mt)
#pragma unroll
      for (int nt = 0; nt < 2; ++nt) {
        sa0[mt][nt] = (f32x4){0.f, 0.f, 0.f, 0.f};
        sa1[mt][nt] = (f32x4){0.f, 0.f, 0.f, 0.f};
      }
    qk(0, kbuf, sa0);
    pv(0, paf[0], vf);
    pexp(0, sa0);
    qk(1, kbuf, sa1);
    pv(1, paf[1], vf);
    pexp(1, sa1);

    __syncthreads();                 // drains K(t+1) DMA; fences Ks/Vt buffer reuse
    if (pre) {                       // V(t+1) -> Vt[pvbuf] (all PV(t-1) reads done)
      *(uint4*)&Vt[pvbuf][vd0][vcp * 8] = vr0;
      *(uint4*)&Vt[pvbuf][vd0 + 64][vcp * 8] = vr1;
    }
  }

  // ---- epilogue PV(NKT-1): P in Pa, V(NKT-1) in Vt[(NKT-1)&1] = Vt[1] ----
  {
    short8 paf[2][2], vf[8];
#pragma unroll
    for (int st = 0; st < 2; ++st)
#pragma unroll
      for (int mt = 0; mt < 2; ++mt)
        paf[st][mt] = *(const short8*)&Pa[wave][st][mt * 16 + l16][quad * 8];
#pragma unroll
    for (int nt8 = 0; nt8 < 8; ++nt8)
      vf[nt8] = *(const short8*)&Vt[1][nt8 * 16 + l16][quad * 8];
    pv(0, paf[0], vf);
    pv(1, paf[1], vf);
  }

  // ---- softmax denominators: per-lane partial covers quad's keys; reduce across quads ----
#pragma unroll
  for (int mt = 0; mt < 2; ++mt)
#pragma unroll
    for (int st = 0; st < 2; ++st) {
      float v = lacc[mt][st];
      v += __shfl_xor(v, 16, 64);
      v += __shfl_xor(v, 32, 64);
      lacc[mt][st] = v;                // denom for q-row = mt*16 + l16 (all lanes)
    }

  float sum = 0.f, ssq = 0.f;
#pragma unroll
  for (int mt = 0; mt < 2; ++mt) {
    float i1[4], i2[4];
#pragma unroll
    for (int r = 0; r < 4; ++r) {
      // output row q = mt*16 + quad*4 + r -> denom lives at lane (quad*4+r)
      i1[r] = 1.f / __shfl(lacc[mt][0], quad * 4 + r, 64);
      i2[r] = lam / __shfl(lacc[mt][1], quad * 4 + r, 64);
    }
#pragma unroll
    for (int nt8 = 0; nt8 < 8; ++nt8)
#pragma unroll
      for (int r = 0; r < 4; ++r) {
        float o = acc[mt][0][nt8][r] * i1[r] - acc[mt][1][nt8][r] * i2[r];
        int row = q0 + wave * 32 + mt * 16 + quad * 4 + r;
        out[((size_t)bh * S + row) * D + nt8 * 16 + l16] = o;
        sum += o; ssq += o * o;
      }
  }
#pragma unroll
  for (int off = 32; off >= 1; off >>= 1) {
    sum += __shfl_xor(sum, off, 64);
    ssq += __shfl_xor(ssq, off, 64);
  }
  if (lane == 0) { sred[wave][0] = sum; sred[wave][1] = ssq; }
  __syncthreads();
  if (tid == 0) {
    float s0 = sred[0][0] + sred[1][0] + sred[2][0] + sred[3][0];
    float s1 = sred[0][1] + sred[1][1] + sred[2][1] + sred[3][1];
    int idx = bh * 16 + qb;
    wsf[64 + idx * 2] = s0;
    wsf[64 + idx * 2 + 1] = s1;
  }
}

// ---------------- kernel 4: group norm (in-place on out) ----------------
__global__ void gn_kernel(float* __restrict__ out, const float* __restrict__ gw,
                          const float* __restrict__ gb, const float* __restrict__ wsf) {
  const int bh = blockIdx.x, part = blockIdx.y;
  const int h = bh & (H - 1);
  float sum = 0.f, ssq = 0.f;
  for (int j = 0; j < 16; ++j) {
    sum += wsf[64 + (bh * 16 + j) * 2];
    ssq += wsf[64 + (bh * 16 + j) * 2 + 1];
  }
  const float invn = 1.f / (float)(S * D);
  const float mean = sum * invn;
  const float var = ssq * invn - mean * mean;
  const float rstd = rsqrtf(var + GN_EPS);
  const float outscale = 1.f - LAM_INIT;
  const float4* g4 = (const float4*)(gw + h * D);
  const float4* b4 = (const float4*)(gb + h * D);
  float4* o4 = (float4*)(out + (size_t)bh * S * D);
  const int chunks_per = (S * D / 4) / 8;
  const int c0 = part * chunks_per;
  for (int c = c0 + threadIdx.x; c < c0 + chunks_per; c += 256) {
    float4 vv = o4[c];
    int d4 = c & 31;
    float4 g = g4[d4], bb = b4[d4];
    vv.x = ((vv.x - mean) * rstd * g.x + bb.x) * outscale;
    vv.y = ((vv.y - mean) * rstd * g.y + bb.y) * outscale;
    vv.z = ((vv.z - mean) * rstd * g.z + bb.z) * outscale;
    vv.w = ((vv.w - mean) * rstd * g.w + bb.w) * outscale;
    o4[c] = vv;
  }
}

extern "C" void kernel_launch(void* const* d_in, const int* in_sizes, int n_in,
                              void* d_out, int out_size, void* d_ws, size_t ws_size,
                              hipStream_t stream) {
  (void)in_sizes; (void)n_in; (void)out_size; (void)ws_size;
  const float* q   = (const float*)d_in[0];
  const float* k   = (const float*)d_in[1];
  const float* v   = (const float*)d_in[2];
  const float* lq1 = (const float*)d_in[3];
  const float* lq2 = (const float*)d_in[4];
  const float* lk1 = (const float*)d_in[5];
  const float* lk2 = (const float*)d_in[6];
  const float* gw  = (const float*)d_in[7];
  const float* gb  = (const float*)d_in[8];
  float* out = (float*)d_out;
  float* wsf = (float*)d_ws;
  unsigned short* vtg = (unsigned short*)((char*)d_ws + 16384);
  unsigned short* kbf = (unsigned short*)((char*)d_ws + 16384 + (size_t)BH * D * S * 2);

  prep_kernel<<<dim3(8192 + BH * 32), dim3(256), 0, stream>>>(k, kbf, v, vtg, lq1, lq2, lk1, lk2, wsf);
  attn_kernel<<<dim3(BH, S / QTILE), dim3(256), 0, stream>>>(q, kbf, vtg, wsf, out);
  gn_kernel<<<dim3(BH, 8), dim3(256), 0, stream>>>(out, gw, gb, wsf);
}